// Round 4
// baseline (688.614 us; speedup 1.0000x reference)
//
#include <hip/hip_runtime.h>
#include <hip/hip_bf16.h>

// HGCNConv on MI355X — correctness-first, minimal-API build.
// HypLinear (mobius_matvec + bias mobius_add) -> HypAgg (edge scatter in
// tangent space) -> HypAct (relu in tangent space). Math in fp32.
//
// Input/output dtype (bf16 vs f32) detected at runtime by detect_kernel
// (flag in ws[97]); all kernels branch on the wave-uniform flag.
//
// ws float layout: [0..95] hyp_bias, [96] ||hb||^2, [97] dtype flag,
//                  [128 .. 128+N*96) fp32 support accumulator.
// xt (logmap0 after HypLinear) lives in d_out (bf16 if out bf16, f32 if out
// f32); final_kernel fully overwrites d_out at the end.

#define DIN 256
#define DOUT 96
#define MAXN 0.996f      // (1 - 4e-3)/sqrt(c)
#define EPS15 1e-15f
#define ATC (1.0f - 1e-7f)

__device__ __forceinline__ float us2f(unsigned short u) {
    unsigned int v = ((unsigned int)u) << 16;
    return __uint_as_float(v);
}

// ---- dtype detector: bf16 data has no huge values; f32 data reinterpreted
// ---- as bf16 has garbage-exponent halves. flag: 1.0 = bf16, 0.0 = f32.
__global__ void detect_kernel(const unsigned short* __restrict__ xraw,
                              float* __restrict__ ws) {
    if (threadIdx.x == 0 && blockIdx.x == 0) {
        int big = 0;
        for (int i = 0; i < 128; i++) {
            float v = us2f(xraw[i]);
            if (!(fabsf(v) < 1e4f)) big = 1;  // catches inf/nan too
        }
        ws[97] = big ? 0.0f : 1.0f;
    }
}

// ---- zero fp32 support -----------------------------------------------------
__global__ void zero_kernel(float* __restrict__ p, long n) {
    long i = (long)blockIdx.x * blockDim.x + threadIdx.x;
    long stride = (long)gridDim.x * blockDim.x;
    for (; i < n; i += stride) p[i] = 0.0f;
}

// ---- hyp_bias = proj(expmap0(bias)), single thread ------------------------
__global__ void hb_kernel(const void* __restrict__ bias,
                          float* __restrict__ ws) {
    if (threadIdx.x != 0 || blockIdx.x != 0) return;
    bool isb = ws[97] != 0.0f;
    float b[DOUT];
    float n2 = 0.0f;
    for (int i = 0; i < DOUT; i++) {
        float v = isb ? us2f(((const unsigned short*)bias)[i])
                      : ((const float*)bias)[i];
        b[i] = v;
        n2 += v * v;
    }
    float bn = fmaxf(sqrtf(n2), EPS15);
    float ef = tanhf(bn) / bn;
    float hn = ef * sqrtf(n2);
    float s = (hn > MAXN) ? MAXN / fmaxf(hn, EPS15) : 1.0f;
    for (int i = 0; i < DOUT; i++) ws[i] = s * ef * b[i];
    float v = s * hn;
    ws[96] = v * v;
}

// ---- HypLinear: one wave per row; plain VALU dot products -----------------
__global__ void hyplinear_kernel(const void* __restrict__ x,
                                 const void* __restrict__ wgt,
                                 float* __restrict__ ws,
                                 void* __restrict__ xtout, int N) {
    const int lane = threadIdx.x & 63;
    const int wv = threadIdx.x >> 6;
    const int row = blockIdx.x * 4 + wv;
    if (row >= N) return;
    const bool isb = ws[97] != 0.0f;

    // load x row: lane holds k = lane*4 .. lane*4+3
    float xs[4];
    if (isb) {
        ushort4 u = *(const ushort4*)((const unsigned short*)x + (size_t)row * DIN + lane * 4);
        xs[0] = us2f(u.x); xs[1] = us2f(u.y); xs[2] = us2f(u.z); xs[3] = us2f(u.w);
    } else {
        float4 f = *(const float4*)((const float*)x + (size_t)row * DIN + lane * 4);
        xs[0] = f.x; xs[1] = f.y; xs[2] = f.z; xs[3] = f.w;
    }
    float xn2 = xs[0]*xs[0] + xs[1]*xs[1] + xs[2]*xs[2] + xs[3]*xs[3];
    for (int m = 32; m >= 1; m >>= 1) xn2 += __shfl_xor(xn2, m, 64);

    // mx = x_row @ W^T : 96 wave-parallel dot products
    float mx0 = 0.0f, mx1 = 0.0f;   // col lane, col 64+lane (lane<32)
    for (int c = 0; c < DOUT; c++) {
        float wvv[4];
        if (isb) {
            ushort4 u = *(const ushort4*)((const unsigned short*)wgt + (size_t)c * DIN + lane * 4);
            wvv[0] = us2f(u.x); wvv[1] = us2f(u.y); wvv[2] = us2f(u.z); wvv[3] = us2f(u.w);
        } else {
            float4 f = *(const float4*)((const float*)wgt + (size_t)c * DIN + lane * 4);
            wvv[0] = f.x; wvv[1] = f.y; wvv[2] = f.z; wvv[3] = f.w;
        }
        float pp = xs[0]*wvv[0] + xs[1]*wvv[1] + xs[2]*wvv[2] + xs[3]*wvv[3];
        for (int m = 32; m >= 1; m >>= 1) pp += __shfl_xor(pp, m, 64);
        if (lane == c) mx0 = pp;
        if (lane + 64 == c) mx1 = pp;
    }

    // hb for this lane's cols
    float hb0 = ws[lane];
    float hb1 = (lane < 32) ? ws[64 + lane] : 0.0f;
    const float hb2 = ws[96];

    // row reductions: ||mx||^2 and mx.hb
    float mxn2 = mx0*mx0 + mx1*mx1;
    float dmh  = mx0*hb0 + mx1*hb1;
    for (int m = 32; m >= 1; m >>= 1) {
        mxn2 += __shfl_xor(mxn2, m, 64);
        dmh  += __shfl_xor(dmh,  m, 64);
    }

    // scalar mobius chain (all lanes redundantly)
    float xn  = fmaxf(sqrtf(xn2), EPS15);
    float mxn = fmaxf(sqrtf(mxn2), EPS15);
    float g   = (mxn / xn) * atanhf(fminf(xn, ATC));
    float tg  = tanhf(g);
    float rs0 = tg / mxn;                    // res = rs0 * mx
    float rn  = rs0 * sqrtf(mxn2);           // ||res||
    float s1  = (rn > MAXN) ? MAXN / fmaxf(rn, EPS15) : 1.0f;
    float al  = s1 * rs0;                    // h = al * mx
    float x2  = al * al * mxn2;
    float xy  = al * dmh;
    float cA  = 1.0f + 2.0f * xy + hb2;
    float cB  = 1.0f - x2;
    float den = fmaxf(1.0f + 2.0f * xy + x2 * hb2, EPS15);
    float p   = cA * al / den;               // o = p*mx + q*hb
    float q   = cB / den;
    float o2  = p*p*mxn2 + 2.0f*p*q*dmh + q*q*hb2;
    float on  = sqrtf(fmaxf(o2, 0.0f));
    float s2  = (on > MAXN) ? MAXN / fmaxf(on, EPS15) : 1.0f;
    float pn  = fmaxf(s2 * on, EPS15);
    float F   = (atanhf(fminf(pn, ATC)) / pn) * s2;   // logmap0 * proj scale
    float Fp  = F * p, Fq = F * q;

    // xt[row][col] = Fp*mx + Fq*hb
    size_t ob = (size_t)row * DOUT;
    float v0 = fmaf(Fp, mx0, Fq * hb0);
    if (isb) ((__hip_bfloat16*)xtout)[ob + lane] = __float2bfloat16(v0);
    else     ((float*)xtout)[ob + lane] = v0;
    if (lane < 32) {
        float v1 = fmaf(Fp, mx1, Fq * hb1);
        if (isb) ((__hip_bfloat16*)xtout)[ob + 64 + lane] = __float2bfloat16(v1);
        else     ((float*)xtout)[ob + 64 + lane] = v1;
    }
}

// ---- edge scatter: support[erow] += ew * xt[ecol] -------------------------
__global__ void scatter_kernel(const void* __restrict__ xt,
                               const void* __restrict__ ew,
                               const int* __restrict__ erow,
                               const int* __restrict__ ecol,
                               float* __restrict__ ws,
                               float* __restrict__ support, int E) {
    int t = threadIdx.x;
    int e = blockIdx.x * 8 + (t >> 5);
    if (e >= E) return;
    const bool isb = ws[97] != 0.0f;
    int l = t & 31;
    int row = erow[e], col = ecol[e];
    float w = isb ? us2f(((const unsigned short*)ew)[e]) : ((const float*)ew)[e];
    float* dst = support + (size_t)row * DOUT;
    size_t sb = (size_t)col * DOUT;
    for (int m = 0; m < 3; m++) {
        int c = l + 32 * m;
        float v = isb ? us2f(((const unsigned short*)xt)[sb + c])
                      : ((const float*)xt)[sb + c];
        atomicAdd(dst + c, w * v);
    }
}

// ---- proj(expmap0(relu(logmap0(proj(expmap0(support)))))) -----------------
__global__ void final_kernel(const float* __restrict__ support,
                             float* __restrict__ ws,
                             void* __restrict__ out, int N) {
    int wv = threadIdx.x >> 6, lane = threadIdx.x & 63;
    int row = blockIdx.x * 4 + wv;
    if (row >= N) return;
    const bool isb = ws[97] != 0.0f;
    const float* u = support + (size_t)row * DOUT;
    float u0 = u[lane];
    float u1 = (lane < 32) ? u[64 + lane] : 0.0f;
    float n2 = u0*u0 + u1*u1;
    for (int m = 32; m >= 1; m >>= 1) n2 += __shfl_xor(n2, m, 64);
    float un = fmaxf(sqrtf(n2), EPS15);
    float ef = tanhf(un) / un;
    float p0 = ef * u0, p1 = ef * u1;
    float pnrm = ef * sqrtf(n2);
    float s = (pnrm > MAXN) ? MAXN / fmaxf(pnrm, EPS15) : 1.0f;
    p0 *= s; p1 *= s; pnrm *= s;
    float pncl = fmaxf(pnrm, EPS15);
    float lf = atanhf(fminf(pncl, ATC)) / pncl;
    float t0 = fmaxf(lf * p0, 0.0f), t1 = fmaxf(lf * p1, 0.0f);  // relu
    float tn2 = t0*t0 + t1*t1;
    for (int m = 32; m >= 1; m >>= 1) tn2 += __shfl_xor(tn2, m, 64);
    float tn = fmaxf(sqrtf(tn2), EPS15);
    float ef2 = tanhf(tn) / tn;
    float en = ef2 * sqrtf(tn2);
    float s2 = (en > MAXN) ? MAXN / fmaxf(en, EPS15) : 1.0f;
    float scale = s2 * ef2;
    size_t ob = (size_t)row * DOUT;
    if (isb) {
        ((__hip_bfloat16*)out)[ob + lane] = __float2bfloat16(scale * t0);
        if (lane < 32)
            ((__hip_bfloat16*)out)[ob + 64 + lane] = __float2bfloat16(scale * t1);
    } else {
        ((float*)out)[ob + lane] = scale * t0;
        if (lane < 32)
            ((float*)out)[ob + 64 + lane] = scale * t1;
    }
}

extern "C" void kernel_launch(void* const* d_in, const int* in_sizes, int n_in,
                              void* d_out, int out_size, void* d_ws, size_t ws_size,
                              hipStream_t stream) {
    const void* x    = d_in[0];
    const void* wgt  = d_in[1];
    const void* bias = d_in[2];
    const void* ew   = d_in[3];
    const int* erow  = (const int*)d_in[4];
    const int* ecol  = (const int*)d_in[5];

    int N = out_size / DOUT;      // 50000
    int E = in_sizes[4];          // 800000
    long nd = (long)N * DOUT;

    float* wsf     = (float*)d_ws;
    float* support = wsf + 128;

    detect_kernel<<<1, 64, 0, stream>>>((const unsigned short*)x, wsf);
    zero_kernel<<<512, 256, 0, stream>>>(support, nd);
    hb_kernel<<<1, 64, 0, stream>>>(bias, wsf);
    hyplinear_kernel<<<(N + 3) / 4, 256, 0, stream>>>(x, wgt, wsf, d_out, N);
    scatter_kernel<<<(E + 7) / 8, 256, 0, stream>>>(d_out, ew, erow, ecol, wsf, support, E);
    final_kernel<<<(N + 3) / 4, 256, 0, stream>>>(support, wsf, d_out, N);
}